// Round 5
// baseline (611.608 us; speedup 1.0000x reference)
//
#include <hip/hip_runtime.h>

#define B_ 2
#define L_ 2048
#define DIM_ 512
#define NH_ 8
#define HD_ 64
#define TOPK_ 512

typedef __attribute__((ext_vector_type(8))) short short8;
typedef __attribute__((ext_vector_type(4))) float f32x4;
typedef unsigned short ushort_t;

__device__ __forceinline__ unsigned f2ord(float f) {
  unsigned u = __float_as_uint(f);
  return (u >> 31) ? ~u : (u | 0x80000000u);
}
__device__ __forceinline__ float ord2f(unsigned k) {
  unsigned u = (k >> 31) ? (k ^ 0x80000000u) : ~k;
  return __uint_as_float(u);
}
// f32 -> bf16 bits, round-to-nearest-even
__device__ __forceinline__ ushort_t bfrne(float f) {
  unsigned u = __float_as_uint(f);
  return (ushort_t)((u + 0x7FFFu + ((u >> 16) & 1u)) >> 16);
}

// ---------------- QKV GEMM: x[4096x512] @ w_qkv^T[512x1536] + b ----------------
// Epilogue splits into bf16 hi/lo panels: Qh/Ql (x0.125 folded), Kh/Kl, and V^T bf16.
__global__ __launch_bounds__(256) void gemm_qkv(
    const float* __restrict__ A, const float* __restrict__ Bw,
    const float* __restrict__ bias,
    ushort_t* __restrict__ Qh, ushort_t* __restrict__ Ql,
    ushort_t* __restrict__ Kh, ushort_t* __restrict__ Kl,
    ushort_t* __restrict__ Vt)
{
  constexpr int BM = 128, BN = 128, BK = 16, TM = 8, TN = 8;
  const int M = B_ * L_, N = 3 * DIM_, K = DIM_;
  __shared__ float As[BK][BM];
  __shared__ float Bs[BK][BN];
  const int tid = threadIdx.x;
  const int m0 = blockIdx.y * BM;
  const int n0 = blockIdx.x * BN;
  constexpr int TX = BN / TN;
  const int tn = (tid % TX) * TN;
  const int tm = (tid / TX) * TM;

  float acc[TM][TN];
#pragma unroll
  for (int i = 0; i < TM; ++i)
#pragma unroll
    for (int j = 0; j < TN; ++j) acc[i][j] = 0.f;

  constexpr int A4 = BM * BK / 4;
  constexpr int B4 = BN * BK / 4;

  for (int k0 = 0; k0 < K; k0 += BK) {
    for (int idx = tid; idx < A4; idx += 256) {
      int e = idx * 4;
      int row = e / BK, col = e % BK;
      float4 v = *(const float4*)(A + (size_t)(m0 + row) * K + k0 + col);
      As[col][row] = v.x; As[col+1][row] = v.y; As[col+2][row] = v.z; As[col+3][row] = v.w;
    }
    for (int idx = tid; idx < B4; idx += 256) {
      int e = idx * 4;
      int row = e / BK, col = e % BK;
      float4 v = *(const float4*)(Bw + (size_t)(n0 + row) * K + k0 + col);
      Bs[col][row] = v.x; Bs[col+1][row] = v.y; Bs[col+2][row] = v.z; Bs[col+3][row] = v.w;
    }
    __syncthreads();
#pragma unroll
    for (int kk = 0; kk < BK; ++kk) {
      float a[TM], b[TN];
#pragma unroll
      for (int i = 0; i < TM; i += 4) *(float4*)&a[i] = *(const float4*)&As[kk][tm + i];
#pragma unroll
      for (int j = 0; j < TN; j += 4) *(float4*)&b[j] = *(const float4*)&Bs[kk][tn + j];
#pragma unroll
      for (int i = 0; i < TM; ++i)
#pragma unroll
        for (int j = 0; j < TN; ++j) acc[i][j] = fmaf(a[i], b[j], acc[i][j]);
    }
    __syncthreads();
  }

#pragma unroll
  for (int i = 0; i < TM; ++i) {
    const int m = m0 + tm + i;
    const int b = m >> 11, l = m & (L_ - 1);
#pragma unroll
    for (int j = 0; j < TN; ++j) {
      const int n = n0 + tn + j;
      float v = acc[i][j] + bias[n];
      const int which = n >> 9, h = (n >> 6) & (NH_ - 1), d = n & (HD_ - 1);
      const int bh = b * NH_ + h;
      if (which == 0) {
        v *= 0.125f;                        // fold attention scale into Q
        ushort_t hi = bfrne(v);
        float hf = __uint_as_float((unsigned)hi << 16);
        ushort_t lo = bfrne(v - hf);
        const size_t o = ((size_t)bh * L_ + l) * HD_ + d;
        Qh[o] = hi; Ql[o] = lo;
      } else if (which == 1) {
        ushort_t hi = bfrne(v);
        float hf = __uint_as_float((unsigned)hi << 16);
        ushort_t lo = bfrne(v - hf);
        const size_t o = ((size_t)bh * L_ + l) * HD_ + d;
        Kh[o] = hi; Kl[o] = lo;
      } else {
        Vt[((size_t)bh * HD_ + d) * L_ + l] = bfrne(v);
      }
    }
  }
}

// ---------------- out = AO @ w_out^T + b (f32 VALU GEMM) ----------------
__global__ __launch_bounds__(256) void gemm_out(
    const float* __restrict__ A, const float* __restrict__ Bw,
    const float* __restrict__ bias, float* __restrict__ out)
{
  constexpr int BM = 64, BN = 64, BK = 16, TM = 4, TN = 4;
  const int N = DIM_, K = DIM_;
  __shared__ float As[BK][BM];
  __shared__ float Bs[BK][BN];
  const int tid = threadIdx.x;
  const int m0 = blockIdx.y * BM;
  const int n0 = blockIdx.x * BN;
  constexpr int TX = BN / TN;
  const int tn = (tid % TX) * TN;
  const int tm = (tid / TX) * TM;

  float acc[TM][TN];
#pragma unroll
  for (int i = 0; i < TM; ++i)
#pragma unroll
    for (int j = 0; j < TN; ++j) acc[i][j] = 0.f;

  constexpr int A4 = BM * BK / 4;
  constexpr int B4 = BN * BK / 4;

  for (int k0 = 0; k0 < K; k0 += BK) {
    for (int idx = tid; idx < A4; idx += 256) {
      int e = idx * 4;
      int row = e / BK, col = e % BK;
      float4 v = *(const float4*)(A + (size_t)(m0 + row) * K + k0 + col);
      As[col][row] = v.x; As[col+1][row] = v.y; As[col+2][row] = v.z; As[col+3][row] = v.w;
    }
    for (int idx = tid; idx < B4; idx += 256) {
      int e = idx * 4;
      int row = e / BK, col = e % BK;
      float4 v = *(const float4*)(Bw + (size_t)(n0 + row) * K + k0 + col);
      Bs[col][row] = v.x; Bs[col+1][row] = v.y; Bs[col+2][row] = v.z; Bs[col+3][row] = v.w;
    }
    __syncthreads();
#pragma unroll
    for (int kk = 0; kk < BK; ++kk) {
      float a[TM], b[TN];
#pragma unroll
      for (int i = 0; i < TM; i += 4) *(float4*)&a[i] = *(const float4*)&As[kk][tm + i];
#pragma unroll
      for (int j = 0; j < TN; j += 4) *(float4*)&b[j] = *(const float4*)&Bs[kk][tn + j];
#pragma unroll
      for (int i = 0; i < TM; ++i)
#pragma unroll
        for (int j = 0; j < TN; ++j) acc[i][j] = fmaf(a[i], b[j], acc[i][j]);
    }
    __syncthreads();
  }

#pragma unroll
  for (int i = 0; i < TM; ++i) {
    const int m = m0 + tm + i;
#pragma unroll
    for (int j = 0; j < TN; ++j)
      out[(size_t)m * N + n0 + tn + j] = acc[i][j] + bias[n0 + tn + j];
  }
}

// ---------------- Attention: 1 block = 8 query rows of one (b,h) ----------------
// 512 threads = 8 waves, 65.7 KB LDS -> 2 blocks/CU (independent phase overlap).
// MFMA q-rows 8-15 are duplicates of 0-7 (C rows 8-15 discarded).
// Phase 1: bf16x3 MFMA scores -> LDS. Phase 2: per-wave exact top-512
// (24-bit bisection) -> dense P row in place. Phase 3: P @ V via MFMA.
__global__ __launch_bounds__(512, 4) void attn_k(
    const ushort_t* __restrict__ Qh, const ushort_t* __restrict__ Ql,
    const ushort_t* __restrict__ Kh, const ushort_t* __restrict__ Kl,
    const ushort_t* __restrict__ Vt, float* __restrict__ AO)
{
  __shared__ float sc[8][2052];    // 65.7 KiB: scores -> dense P -> reduce buffer
  __shared__ float invs[8];

  const int tid = threadIdx.x, lane = tid & 63, wid = tid >> 6;   // 8 waves
  const int bh = blockIdx.x >> 8;           // 256 blocks per bh
  const int l0 = (blockIdx.x & 255) << 3;   // 8 rows per block
  const int arow = lane & 15, agrp = lane >> 4;

  // Q A-fragments: rows l0..l0+7, rows 8-15 duplicate rows 0-7 (discarded)
  const size_t qbase = ((size_t)bh * L_ + l0 + (arow & 7)) * HD_ + agrp * 8;
  const short8 qh0 = *(const short8*)(Qh + qbase);
  const short8 qh1 = *(const short8*)(Qh + qbase + 32);
  const short8 ql0 = *(const short8*)(Ql + qbase);
  const short8 ql1 = *(const short8*)(Ql + qbase + 32);

  // ---- Phase 1: scores. Wave wid owns keys [wid*256, wid*256+256) ----
  {
    const int key00 = wid << 8;
#pragma unroll 4
    for (int t = 0; t < 16; ++t) {
      const int key0 = key00 + t * 16;
      const size_t ka = ((size_t)bh * L_ + key0 + arow) * HD_ + agrp * 8;
      const short8 kh0 = *(const short8*)(Kh + ka);
      const short8 kh1 = *(const short8*)(Kh + ka + 32);
      const short8 kl0 = *(const short8*)(Kl + ka);
      const short8 kl1 = *(const short8*)(Kl + ka + 32);
      f32x4 acc = {0.f, 0.f, 0.f, 0.f};
      acc = __builtin_amdgcn_mfma_f32_16x16x32_bf16(qh0, kh0, acc, 0, 0, 0);
      acc = __builtin_amdgcn_mfma_f32_16x16x32_bf16(qh1, kh1, acc, 0, 0, 0);
      acc = __builtin_amdgcn_mfma_f32_16x16x32_bf16(ql0, kh0, acc, 0, 0, 0);
      acc = __builtin_amdgcn_mfma_f32_16x16x32_bf16(ql1, kh1, acc, 0, 0, 0);
      acc = __builtin_amdgcn_mfma_f32_16x16x32_bf16(qh0, kl0, acc, 0, 0, 0);
      acc = __builtin_amdgcn_mfma_f32_16x16x32_bf16(qh1, kl1, acc, 0, 0, 0);
      // C layout: col(key) = lane&15, row(q) = (lane>>4)*4 + reg; keep rows 0-7
      if (agrp < 2) {
#pragma unroll
        for (int rr = 0; rr < 4; ++rr) sc[agrp * 4 + rr][key0 + arow] = acc[rr];
      }
    }
  }
  __syncthreads();

  // ---- Phase 2: exact top-512 selection, row = wid; dense P written in place ----
  {
    const int r = wid;
    unsigned keys[32];
    float mx = -3.0e38f;
#pragma unroll
    for (int t = 0; t < 32; ++t) {
      const float s = sc[r][lane + 64 * t];
      keys[t] = f2ord(s);
      mx = fmaxf(mx, s);
    }
#pragma unroll
    for (int off = 32; off; off >>= 1) mx = fmaxf(mx, __shfl_xor(mx, off));

    unsigned P = 0;
#pragma unroll 1
    for (int bit = 31; bit >= 8; --bit) {   // 24 bits: 2^8-ulp ties < score noise
      const unsigned cand = P | (1u << bit);
      int c = 0;
#pragma unroll
      for (int t = 0; t < 32; ++t)
        c += (int)__popcll(__ballot(keys[t] >= cand));
      if (c >= TOPK_) P = cand;
    }

    int base = 0;
    float part = 0.f;
#pragma unroll
    for (int t = 0; t < 32; ++t) {
      const bool sel = keys[t] >= P;
      const unsigned long long mb = __ballot(sel);
      const int pos = base + (int)__popcll(mb & ((1ull << lane) - 1ull));
      const float p = (sel && pos < TOPK_) ? __expf(ord2f(keys[t]) - mx) : 0.f;
      sc[r][lane + 64 * t] = p;             // dense P (0 where unselected)
      part += p;
      base += (int)__popcll(mb);
    }
#pragma unroll
    for (int off = 32; off; off >>= 1) part += __shfl_xor(part, off);
    if (lane == 0) invs[r] = 1.f / part;
  }
  __syncthreads();

  // ---- Phase 3: PV = P(8x2048) @ V(2048x64); wave wid does keys [wid*256,+256) ----
  f32x4 o0 = {0.f,0.f,0.f,0.f}, o1 = o0, o2 = o0, o3 = o0;
  {
    const int key00 = wid << 8;
#pragma unroll 2
    for (int ks = 0; ks < 8; ++ks) {
      const int kb = key00 + ks * 32 + agrp * 8;
      float pf[8];
      *(float4*)&pf[0] = *(const float4*)&sc[arow & 7][kb];
      *(float4*)&pf[4] = *(const float4*)&sc[arow & 7][kb + 4];
      short8 pa;
#pragma unroll
      for (int j = 0; j < 8; ++j) pa[j] = (short)bfrne(pf[j]);
      const size_t vb0 = ((size_t)bh * HD_ + arow) * L_ + kb;
      const short8 v0 = *(const short8*)(Vt + vb0);
      const short8 v1 = *(const short8*)(Vt + vb0 + 16 * L_);
      const short8 v2 = *(const short8*)(Vt + vb0 + 32 * L_);
      const short8 v3 = *(const short8*)(Vt + vb0 + 48 * L_);
      o0 = __builtin_amdgcn_mfma_f32_16x16x32_bf16(pa, v0, o0, 0, 0, 0);
      o1 = __builtin_amdgcn_mfma_f32_16x16x32_bf16(pa, v1, o1, 0, 0, 0);
      o2 = __builtin_amdgcn_mfma_f32_16x16x32_bf16(pa, v2, o2, 0, 0, 0);
      o3 = __builtin_amdgcn_mfma_f32_16x16x32_bf16(pa, v3, o3, 0, 0, 0);
    }
  }
  __syncthreads();                 // all P reads done; sc reusable

  // ---- cross-wave reduction of 8 partial Out(8x64) tiles ----
  float* red = &sc[0][0];          // [8 waves][8 rows][64 d] f32 = 16 KiB
  if (agrp < 2) {
#pragma unroll
    for (int rr = 0; rr < 4; ++rr) {
      const int row = agrp * 4 + rr;
      red[wid * 512 + row * 64 +  0 + arow] = o0[rr];
      red[wid * 512 + row * 64 + 16 + arow] = o1[rr];
      red[wid * 512 + row * 64 + 32 + arow] = o2[rr];
      red[wid * 512 + row * 64 + 48 + arow] = o3[rr];
    }
  }
  __syncthreads();
  {
    const int b = bh >> 3, h = bh & 7;
    const int r = tid >> 6, d = tid & 63;
    float s = 0.f;
#pragma unroll
    for (int w = 0; w < 8; ++w) s += red[w * 512 + r * 64 + d];
    AO[((size_t)(b * L_ + l0 + r)) * DIM_ + h * HD_ + d] = s * invs[r];
  }
}

extern "C" void kernel_launch(void* const* d_in, const int* in_sizes, int n_in,
                              void* d_out, int out_size, void* d_ws, size_t ws_size,
                              hipStream_t stream) {
  const float* x     = (const float*)d_in[0];
  const float* w_qkv = (const float*)d_in[1];
  const float* b_qkv = (const float*)d_in[2];
  const float* w_out = (const float*)d_in[3];
  const float* b_out = (const float*)d_in[4];
  float* out = (float*)d_out;

  const size_t NE = (size_t)B_ * NH_ * L_ * HD_;   // 2,097,152
  ushort_t* Qh = (ushort_t*)d_ws;
  ushort_t* Ql = Qh + NE;
  ushort_t* Kh = Ql + NE;
  ushort_t* Kl = Kh + NE;
  ushort_t* Vt = Kl + NE;
  float*    AO = (float*)(Vt + NE);                // [b][l][512] f32, 8 MB
  const int M = B_ * L_;                           // 4096

  gemm_qkv<<<dim3((3 * DIM_) / 128, M / 128), 256, 0, stream>>>(
      x, w_qkv, b_qkv, Qh, Ql, Kh, Kl, Vt);
  attn_k<<<dim3(B_ * NH_ * (L_ / 8)), 512, 0, stream>>>(Qh, Ql, Kh, Kl, Vt, AO);
  gemm_out<<<dim3(DIM_ / 64, M / 64), 256, 0, stream>>>(AO, w_out, b_out, out);
}

// Round 6
// 487.931 us; speedup vs baseline: 1.2535x; 1.2535x over previous
//
#include <hip/hip_runtime.h>

#define B_ 2
#define L_ 2048
#define DIM_ 512
#define NH_ 8
#define HD_ 64
#define TOPK_ 512

typedef __attribute__((ext_vector_type(8))) short short8;
typedef __attribute__((ext_vector_type(4))) float f32x4;
typedef unsigned short ushort_t;

__device__ __forceinline__ unsigned f2ord(float f) {
  unsigned u = __float_as_uint(f);
  return (u >> 31) ? ~u : (u | 0x80000000u);
}
__device__ __forceinline__ float ord2f(unsigned k) {
  unsigned u = (k >> 31) ? (k ^ 0x80000000u) : ~k;
  return __uint_as_float(u);
}
// f32 -> bf16 bits, round-to-nearest-even
__device__ __forceinline__ ushort_t bfrne(float f) {
  unsigned u = __float_as_uint(f);
  return (ushort_t)((u + 0x7FFFu + ((u >> 16) & 1u)) >> 16);
}

// ---------------- QKV GEMM: x[4096x512] @ w_qkv^T[512x1536] + b ----------------
// Epilogue splits into bf16 hi/lo panels: Qh/Ql (x0.125 folded), Kh/Kl, and V^T bf16.
__global__ __launch_bounds__(256) void gemm_qkv(
    const float* __restrict__ A, const float* __restrict__ Bw,
    const float* __restrict__ bias,
    ushort_t* __restrict__ Qh, ushort_t* __restrict__ Ql,
    ushort_t* __restrict__ Kh, ushort_t* __restrict__ Kl,
    ushort_t* __restrict__ Vt)
{
  constexpr int BM = 128, BN = 128, BK = 16, TM = 8, TN = 8;
  const int M = B_ * L_, N = 3 * DIM_, K = DIM_;
  __shared__ float As[BK][BM];
  __shared__ float Bs[BK][BN];
  const int tid = threadIdx.x;
  const int m0 = blockIdx.y * BM;
  const int n0 = blockIdx.x * BN;
  constexpr int TX = BN / TN;
  const int tn = (tid % TX) * TN;
  const int tm = (tid / TX) * TM;

  float acc[TM][TN];
#pragma unroll
  for (int i = 0; i < TM; ++i)
#pragma unroll
    for (int j = 0; j < TN; ++j) acc[i][j] = 0.f;

  constexpr int A4 = BM * BK / 4;
  constexpr int B4 = BN * BK / 4;

  for (int k0 = 0; k0 < K; k0 += BK) {
    for (int idx = tid; idx < A4; idx += 256) {
      int e = idx * 4;
      int row = e / BK, col = e % BK;
      float4 v = *(const float4*)(A + (size_t)(m0 + row) * K + k0 + col);
      As[col][row] = v.x; As[col+1][row] = v.y; As[col+2][row] = v.z; As[col+3][row] = v.w;
    }
    for (int idx = tid; idx < B4; idx += 256) {
      int e = idx * 4;
      int row = e / BK, col = e % BK;
      float4 v = *(const float4*)(Bw + (size_t)(n0 + row) * K + k0 + col);
      Bs[col][row] = v.x; Bs[col+1][row] = v.y; Bs[col+2][row] = v.z; Bs[col+3][row] = v.w;
    }
    __syncthreads();
#pragma unroll
    for (int kk = 0; kk < BK; ++kk) {
      float a[TM], b[TN];
#pragma unroll
      for (int i = 0; i < TM; i += 4) *(float4*)&a[i] = *(const float4*)&As[kk][tm + i];
#pragma unroll
      for (int j = 0; j < TN; j += 4) *(float4*)&b[j] = *(const float4*)&Bs[kk][tn + j];
#pragma unroll
      for (int i = 0; i < TM; ++i)
#pragma unroll
        for (int j = 0; j < TN; ++j) acc[i][j] = fmaf(a[i], b[j], acc[i][j]);
    }
    __syncthreads();
  }

#pragma unroll
  for (int i = 0; i < TM; ++i) {
    const int m = m0 + tm + i;
    const int b = m >> 11, l = m & (L_ - 1);
#pragma unroll
    for (int j = 0; j < TN; ++j) {
      const int n = n0 + tn + j;
      float v = acc[i][j] + bias[n];
      const int which = n >> 9, h = (n >> 6) & (NH_ - 1), d = n & (HD_ - 1);
      const int bh = b * NH_ + h;
      if (which == 0) {
        v *= 0.125f;                        // fold attention scale into Q
        ushort_t hi = bfrne(v);
        float hf = __uint_as_float((unsigned)hi << 16);
        ushort_t lo = bfrne(v - hf);
        const size_t o = ((size_t)bh * L_ + l) * HD_ + d;
        Qh[o] = hi; Ql[o] = lo;
      } else if (which == 1) {
        ushort_t hi = bfrne(v);
        float hf = __uint_as_float((unsigned)hi << 16);
        ushort_t lo = bfrne(v - hf);
        const size_t o = ((size_t)bh * L_ + l) * HD_ + d;
        Kh[o] = hi; Kl[o] = lo;
      } else {
        Vt[((size_t)bh * HD_ + d) * L_ + l] = bfrne(v);
      }
    }
  }
}

// ---------------- out = AO @ w_out^T + b (f32 VALU GEMM) ----------------
__global__ __launch_bounds__(256) void gemm_out(
    const float* __restrict__ A, const float* __restrict__ Bw,
    const float* __restrict__ bias, float* __restrict__ out)
{
  constexpr int BM = 64, BN = 64, BK = 16, TM = 4, TN = 4;
  const int N = DIM_, K = DIM_;
  __shared__ float As[BK][BM];
  __shared__ float Bs[BK][BN];
  const int tid = threadIdx.x;
  const int m0 = blockIdx.y * BM;
  const int n0 = blockIdx.x * BN;
  constexpr int TX = BN / TN;
  const int tn = (tid % TX) * TN;
  const int tm = (tid / TX) * TM;

  float acc[TM][TN];
#pragma unroll
  for (int i = 0; i < TM; ++i)
#pragma unroll
    for (int j = 0; j < TN; ++j) acc[i][j] = 0.f;

  constexpr int A4 = BM * BK / 4;
  constexpr int B4 = BN * BK / 4;

  for (int k0 = 0; k0 < K; k0 += BK) {
    for (int idx = tid; idx < A4; idx += 256) {
      int e = idx * 4;
      int row = e / BK, col = e % BK;
      float4 v = *(const float4*)(A + (size_t)(m0 + row) * K + k0 + col);
      As[col][row] = v.x; As[col+1][row] = v.y; As[col+2][row] = v.z; As[col+3][row] = v.w;
    }
    for (int idx = tid; idx < B4; idx += 256) {
      int e = idx * 4;
      int row = e / BK, col = e % BK;
      float4 v = *(const float4*)(Bw + (size_t)(n0 + row) * K + k0 + col);
      Bs[col][row] = v.x; Bs[col+1][row] = v.y; Bs[col+2][row] = v.z; Bs[col+3][row] = v.w;
    }
    __syncthreads();
#pragma unroll
    for (int kk = 0; kk < BK; ++kk) {
      float a[TM], b[TN];
#pragma unroll
      for (int i = 0; i < TM; i += 4) *(float4*)&a[i] = *(const float4*)&As[kk][tm + i];
#pragma unroll
      for (int j = 0; j < TN; j += 4) *(float4*)&b[j] = *(const float4*)&Bs[kk][tn + j];
#pragma unroll
      for (int i = 0; i < TM; ++i)
#pragma unroll
        for (int j = 0; j < TN; ++j) acc[i][j] = fmaf(a[i], b[j], acc[i][j]);
    }
    __syncthreads();
  }

#pragma unroll
  for (int i = 0; i < TM; ++i) {
    const int m = m0 + tm + i;
#pragma unroll
    for (int j = 0; j < TN; ++j)
      out[(size_t)m * N + n0 + tn + j] = acc[i][j] + bias[n0 + tn + j];
  }
}

// ---------------- Attention: 1 block = 16 query rows of one (b,h) ----------------
// 1024 threads = 16 waves, 131 KB LDS (1 block/CU). Latency-hiding version:
// phase 1 K loads 2-deep reg-pipelined + split MFMA chains; V tiles prefetched
// across the selection phase (selection-independent addresses); phase 3 2-deep.
__global__ __launch_bounds__(1024, 1) void attn_k(
    const ushort_t* __restrict__ Qh, const ushort_t* __restrict__ Ql,
    const ushort_t* __restrict__ Kh, const ushort_t* __restrict__ Kl,
    const ushort_t* __restrict__ Vt, float* __restrict__ AO)
{
  __shared__ float sc[16][2052];   // 128.3 KiB: scores -> dense P -> reduce buffer
  __shared__ float invs[16];

  const int tid = threadIdx.x, lane = tid & 63, wid = tid >> 6;   // 16 waves
  const int bh = blockIdx.x >> 7;           // 128 blocks per bh
  const int l0 = (blockIdx.x & 127) << 4;   // 16 rows per block
  const int arow = lane & 15, agrp = lane >> 4;
  const int key00 = wid << 7;               // this wave's 128-key slice

  // Q A-fragments (rows l0..l0+15), loaded by every wave (cheap)
  const size_t qbase = ((size_t)bh * L_ + l0 + arow) * HD_ + agrp * 8;
  const short8 qh0 = *(const short8*)(Qh + qbase);
  const short8 qh1 = *(const short8*)(Qh + qbase + 32);
  const short8 ql0 = *(const short8*)(Ql + qbase);
  const short8 ql1 = *(const short8*)(Ql + qbase + 32);

  // ---- Phase 1: scores, 2-deep K pipeline. Wave owns keys [key00, key00+128) ----
  {
    const size_t ka0 = ((size_t)bh * L_ + key00 + arow) * HD_ + agrp * 8;
    short8 bh0[2], bh1[2], bl0[2], bl1[2];
    bh0[0] = *(const short8*)(Kh + ka0);
    bh1[0] = *(const short8*)(Kh + ka0 + 32);
    bl0[0] = *(const short8*)(Kl + ka0);
    bl1[0] = *(const short8*)(Kl + ka0 + 32);
#pragma unroll
    for (int t = 0; t < 8; ++t) {
      const int cur = t & 1, nxt = cur ^ 1;
      if (t < 7) {
        const size_t ka = ka0 + (size_t)(t + 1) * 16 * HD_;
        bh0[nxt] = *(const short8*)(Kh + ka);
        bh1[nxt] = *(const short8*)(Kh + ka + 32);
        bl0[nxt] = *(const short8*)(Kl + ka);
        bl1[nxt] = *(const short8*)(Kl + ka + 32);
      }
      // two independent 3-chains (d-low / d-high), summed at the end
      f32x4 aA = {0.f, 0.f, 0.f, 0.f}, aB = {0.f, 0.f, 0.f, 0.f};
      aA = __builtin_amdgcn_mfma_f32_16x16x32_bf16(qh0, bh0[cur], aA, 0, 0, 0);
      aB = __builtin_amdgcn_mfma_f32_16x16x32_bf16(qh1, bh1[cur], aB, 0, 0, 0);
      aA = __builtin_amdgcn_mfma_f32_16x16x32_bf16(ql0, bh0[cur], aA, 0, 0, 0);
      aB = __builtin_amdgcn_mfma_f32_16x16x32_bf16(ql1, bh1[cur], aB, 0, 0, 0);
      aA = __builtin_amdgcn_mfma_f32_16x16x32_bf16(qh0, bl0[cur], aA, 0, 0, 0);
      aB = __builtin_amdgcn_mfma_f32_16x16x32_bf16(qh1, bl1[cur], aB, 0, 0, 0);
      const int key0 = key00 + t * 16;
      // C layout: col(key) = lane&15, row(q) = (lane>>4)*4 + reg  [HW-verified]
#pragma unroll
      for (int rr = 0; rr < 4; ++rr)
        sc[agrp * 4 + rr][key0 + arow] = aA[rr] + aB[rr];
    }
  }
  __syncthreads();

  // ---- V prefetch for phase-3 iters 0,1 (addresses are selection-independent;
  //      loads fly during the whole selection phase) ----
  const size_t vrow = ((size_t)bh * HD_ + arow) * L_;
  short8 va0, va1, va2, va3, vb0, vb1, vb2, vb3;
  {
    const size_t p0 = vrow + key00 + 0 * 32 + agrp * 8;
    va0 = *(const short8*)(Vt + p0);
    va1 = *(const short8*)(Vt + p0 + 16 * L_);
    va2 = *(const short8*)(Vt + p0 + 32 * L_);
    va3 = *(const short8*)(Vt + p0 + 48 * L_);
    const size_t p1 = vrow + key00 + 1 * 32 + agrp * 8;
    vb0 = *(const short8*)(Vt + p1);
    vb1 = *(const short8*)(Vt + p1 + 16 * L_);
    vb2 = *(const short8*)(Vt + p1 + 32 * L_);
    vb3 = *(const short8*)(Vt + p1 + 48 * L_);
  }

  // ---- Phase 2: exact top-512 selection, row = wid; dense P written in place ----
  {
    const int r = wid;
    unsigned keys[32];
    float mx = -3.0e38f;
#pragma unroll
    for (int t = 0; t < 32; ++t) {
      const float s = sc[r][lane + 64 * t];
      keys[t] = f2ord(s);
      mx = fmaxf(mx, s);
    }
#pragma unroll
    for (int off = 32; off; off >>= 1) mx = fmaxf(mx, __shfl_xor(mx, off));

    unsigned P = 0;
#pragma unroll 1
    for (int bit = 31; bit >= 8; --bit) {   // 24 bits: 2^8-ulp ties < score noise
      const unsigned cand = P | (1u << bit);
      int c = 0;
#pragma unroll
      for (int t = 0; t < 32; ++t)
        c += (int)__popcll(__ballot(keys[t] >= cand));
      if (c >= TOPK_) P = cand;
    }

    int base = 0;
    float part = 0.f;
#pragma unroll
    for (int t = 0; t < 32; ++t) {
      const bool sel = keys[t] >= P;
      const unsigned long long mb = __ballot(sel);
      const int pos = base + (int)__popcll(mb & ((1ull << lane) - 1ull));
      const float p = (sel && pos < TOPK_) ? __expf(ord2f(keys[t]) - mx) : 0.f;
      sc[r][lane + 64 * t] = p;             // dense P (0 where unselected)
      part += p;
      base += (int)__popcll(mb);
    }
#pragma unroll
    for (int off = 32; off; off >>= 1) part += __shfl_xor(part, off);
    if (lane == 0) invs[r] = 1.f / part;
  }
  __syncthreads();

  // ---- Phase 3: PV = P(16x2048) @ V(2048x64), 2-deep pipeline over 4 iters ----
  f32x4 o0 = {0.f,0.f,0.f,0.f}, o1 = o0, o2 = o0, o3 = o0;
  {
    short8 vA[4] = {va0, va1, va2, va3};
    short8 vB[4] = {vb0, vb1, vb2, vb3};
#pragma unroll
    for (int ks = 0; ks < 4; ++ks) {
      // P fragment for this key slice
      const int kb = key00 + ks * 32 + agrp * 8;
      float pf[8];
      *(float4*)&pf[0] = *(const float4*)&sc[arow][kb];
      *(float4*)&pf[4] = *(const float4*)&sc[arow][kb + 4];
      short8 pa;
#pragma unroll
      for (int j = 0; j < 8; ++j) pa[j] = (short)bfrne(pf[j]);

      short8 v0 = (ks & 1) ? vB[0] : vA[0];
      short8 v1 = (ks & 1) ? vB[1] : vA[1];
      short8 v2 = (ks & 1) ? vB[2] : vA[2];
      short8 v3 = (ks & 1) ? vB[3] : vA[3];
      if (ks < 2) {   // refill the buffer just consumed with iter ks+2
        const size_t pn = vrow + key00 + (ks + 2) * 32 + agrp * 8;
        if (ks & 1) {
          vB[0] = *(const short8*)(Vt + pn);
          vB[1] = *(const short8*)(Vt + pn + 16 * L_);
          vB[2] = *(const short8*)(Vt + pn + 32 * L_);
          vB[3] = *(const short8*)(Vt + pn + 48 * L_);
        } else {
          vA[0] = *(const short8*)(Vt + pn);
          vA[1] = *(const short8*)(Vt + pn + 16 * L_);
          vA[2] = *(const short8*)(Vt + pn + 32 * L_);
          vA[3] = *(const short8*)(Vt + pn + 48 * L_);
        }
      }
      o0 = __builtin_amdgcn_mfma_f32_16x16x32_bf16(pa, v0, o0, 0, 0, 0);
      o1 = __builtin_amdgcn_mfma_f32_16x16x32_bf16(pa, v1, o1, 0, 0, 0);
      o2 = __builtin_amdgcn_mfma_f32_16x16x32_bf16(pa, v2, o2, 0, 0, 0);
      o3 = __builtin_amdgcn_mfma_f32_16x16x32_bf16(pa, v3, o3, 0, 0, 0);
    }
  }
  __syncthreads();                 // all P reads done; sc reusable

  // ---- cross-wave reduction of 16 partial Out(16x64) tiles ----
  float* red = &sc[0][0];          // [16 waves][16 rows][64 d] f32 = 64 KiB
  {
#pragma unroll
    for (int rr = 0; rr < 4; ++rr) {
      const int row = agrp * 4 + rr;
      red[wid * 1024 + row * 64 +  0 + arow] = o0[rr];
      red[wid * 1024 + row * 64 + 16 + arow] = o1[rr];
      red[wid * 1024 + row * 64 + 32 + arow] = o2[rr];
      red[wid * 1024 + row * 64 + 48 + arow] = o3[rr];
    }
  }
  __syncthreads();
  {
    const int b = bh >> 3, h = bh & 7;
    const int r = tid >> 6, d = tid & 63;
    float s = 0.f;
#pragma unroll
    for (int w = 0; w < 16; ++w) s += red[w * 1024 + tid];
    AO[((size_t)(b * L_ + l0 + r)) * DIM_ + h * HD_ + d] = s * invs[r];
  }
}

extern "C" void kernel_launch(void* const* d_in, const int* in_sizes, int n_in,
                              void* d_out, int out_size, void* d_ws, size_t ws_size,
                              hipStream_t stream) {
  const float* x     = (const float*)d_in[0];
  const float* w_qkv = (const float*)d_in[1];
  const float* b_qkv = (const float*)d_in[2];
  const float* w_out = (const float*)d_in[3];
  const float* b_out = (const float*)d_in[4];
  float* out = (float*)d_out;

  const size_t NE = (size_t)B_ * NH_ * L_ * HD_;   // 2,097,152
  ushort_t* Qh = (ushort_t*)d_ws;
  ushort_t* Ql = Qh + NE;
  ushort_t* Kh = Ql + NE;
  ushort_t* Kl = Kh + NE;
  ushort_t* Vt = Kl + NE;
  float*    AO = (float*)(Vt + NE);                // [b][l][512] f32, 8 MB
  const int M = B_ * L_;                           // 4096

  gemm_qkv<<<dim3((3 * DIM_) / 128, M / 128), 256, 0, stream>>>(
      x, w_qkv, b_qkv, Qh, Ql, Kh, Kl, Vt);
  attn_k<<<dim3(B_ * NH_ * (L_ / 16)), 1024, 0, stream>>>(Qh, Ql, Kh, Kl, Vt, AO);
  gemm_out<<<dim3(DIM_ / 64, M / 64), 256, 0, stream>>>(AO, w_out, b_out, out);
}